// Round 1
// baseline (118.330 us; speedup 1.0000x reference)
//
#include <hip/hip_runtime.h>
#include <hip/hip_bf16.h>
#include <stdint.h>

// Problem constants (fixed by reference: N=M=16384, D=64, T=1)
#define N_ROWS 16384
#define D_DIM 64
#define BN 128
#define BM 128
#define NSPLIT 4
#define COLS_PER_SPLIT (N_ROWS / NSPLIT)   // 4096
#define N_ITER (COLS_PER_SPLIT / BM)       // 32
#define SHIFT2 64.0f                        // LSE shift, log2 domain
#define LOG2E 1.44269504088896340736f
#define LN2 0.69314718055994530942f

using short8  = __attribute__((ext_vector_type(8))) short;
using float4v = __attribute__((ext_vector_type(4))) float;

// ---------- bf16 helpers (manual, version-independent) ----------
__device__ __forceinline__ unsigned short f2bf(float f) {
  unsigned u = __float_as_uint(f);
  unsigned r = (u + 0x7fffu + ((u >> 16) & 1u)) >> 16;   // RNE
  return (unsigned short)r;
}
__device__ __forceinline__ float blo(unsigned u) { return __uint_as_float(u << 16); }
__device__ __forceinline__ float bhi(unsigned u) { return __uint_as_float(u & 0xffff0000u); }

// ---------- async global->LDS 16B ----------
__device__ __forceinline__ void async_stage_16(const void* g, void* l) {
  __builtin_amdgcn_global_load_lds(
      (const __attribute__((address_space(1))) uint32_t*)g,
      (__attribute__((address_space(3))) uint32_t*)l, 16, 0, 0);
}

// Stage one 128-row x 64-bf16 (128 B/row) tile into LDS with XOR chunk swizzle.
// LDS slot (row, cs) holds global chunk c = cs ^ (row&7). 16 wave-instrs total,
// 4 per wave; instr t covers rows [t*8, t*8+8), lane supplies its own gaddr,
// dest is lds + t*1024 + lane*16 (contiguous in lane order per the HW rule).
__device__ __forceinline__ void stage_tile(const uint8_t* gbase, uint8_t* lds,
                                           int wave, int lane) {
#pragma unroll
  for (int q = 0; q < 4; ++q) {
    int t = wave * 4 + q;
    int row = t * 8 + (lane >> 3);
    int c = (lane & 7) ^ (row & 7);
    async_stage_16(gbase + row * 128 + c * 16, lds + t * 1024 + lane * 16);
  }
}

// ---------- prep: q' = logits*log2e - log2(noise) -> bf16 ; targets -> bf16 ----------
__global__ void prep_kernel(const float4* __restrict__ lg,
                            const float4* __restrict__ tg,
                            const float* __restrict__ noise,
                            ushort4* __restrict__ qa,
                            ushort4* __restrict__ tb) {
  int i = blockIdx.x * blockDim.x + threadIdx.x;   // 0 .. 262143 (1M floats / 4)
  int d4 = (i & 15) << 2;                          // 16 float4 per 64-elem row
  float4 l = lg[i];
  float4 t = tg[i];
  float c0 = log2f(noise[d4 + 0]);
  float c1 = log2f(noise[d4 + 1]);
  float c2 = log2f(noise[d4 + 2]);
  float c3 = log2f(noise[d4 + 3]);
  ushort4 ua, ub;
  ua.x = f2bf(l.x * LOG2E - c0);
  ua.y = f2bf(l.y * LOG2E - c1);
  ua.z = f2bf(l.z * LOG2E - c2);
  ua.w = f2bf(l.w * LOG2E - c3);
  ub.x = f2bf(t.x);
  ub.y = f2bf(t.y);
  ub.z = f2bf(t.z);
  ub.w = f2bf(t.w);
  qa[i] = ua;
  tb[i] = ub;
}

// ---------- flash: per-row sum of 2^(s' - 64) over this block's column split ----------
__global__ __launch_bounds__(256, 2) void flash_kernel(
    const uint8_t* __restrict__ qa,   // bf16 [16384][64], pre-scaled by log2e
    const uint8_t* __restrict__ tb,   // bf16 [16384][64]
    float* __restrict__ row_sums) {   // [16384], pre-zeroed
  __shared__ __align__(16) uint8_t ldsA[BN * 128];
  __shared__ __align__(16) uint8_t ldsB[BM * 128];

  const int bid = blockIdx.x;        // 0..511
  const int rb = bid >> 2;           // row block 0..127
  const int sp = bid & 3;            // M split 0..3
  const int tid = threadIdx.x;
  const int wave = tid >> 6;
  const int lane = tid & 63;

  const int row0 = rb * BN;
  const int col0 = sp * COLS_PER_SPLIT;

  stage_tile(qa + (size_t)row0 * 128, ldsA, wave, lane);
  stage_tile(tb + (size_t)col0 * 128, ldsB, wave, lane);
  __syncthreads();

  const int rows_off = (wave >> 1) * 64;   // wave's 64-row region
  const int cols_off = (wave & 1) * 64;    // wave's 64-col region

  // A fragments are invariant across the whole M sweep: load once.
  short8 afrag[4][2];
#pragma unroll
  for (int i = 0; i < 4; ++i)
#pragma unroll
    for (int k2 = 0; k2 < 2; ++k2) {
      int r = rows_off + i * 16 + (lane & 15);
      int c = (k2 * 4 + (lane >> 4)) ^ (r & 7);
      afrag[i][k2] = *(const short8*)(ldsA + r * 128 + c * 16);
    }

  float sums[4][4];
#pragma unroll
  for (int i = 0; i < 4; ++i)
#pragma unroll
    for (int r = 0; r < 4; ++r) sums[i][r] = 0.f;

  for (int it = 0; it < N_ITER; ++it) {
    // read this tile's B fragments into registers
    short8 bfrag[4][2];
#pragma unroll
    for (int j = 0; j < 4; ++j)
#pragma unroll
      for (int k2 = 0; k2 < 2; ++k2) {
        int r = cols_off + j * 16 + (lane & 15);
        int c = (k2 * 4 + (lane >> 4)) ^ (r & 7);
        bfrag[j][k2] = *(const short8*)(ldsB + r * 128 + c * 16);
      }
    __syncthreads();   // all waves done reading ldsB
    if (it + 1 < N_ITER)
      stage_tile(tb + (size_t)(col0 + (it + 1) * BM) * 128, ldsB, wave, lane);

    // compute 64x64 scores for this wave; C init = -SHIFT2 folds the LSE shift
    float4v acc[4][4];
#pragma unroll
    for (int i = 0; i < 4; ++i)
#pragma unroll
      for (int j = 0; j < 4; ++j) {
        float4v a0 = {-SHIFT2, -SHIFT2, -SHIFT2, -SHIFT2};
        a0 = __builtin_amdgcn_mfma_f32_16x16x32_bf16(afrag[i][0], bfrag[j][0], a0, 0, 0, 0);
        a0 = __builtin_amdgcn_mfma_f32_16x16x32_bf16(afrag[i][1], bfrag[j][1], a0, 0, 0, 0);
        acc[i][j] = a0;
      }
    // exp2 + accumulate per-row partial sums
    // C layout: col = lane&15, row = (lane>>4)*4 + r  -> sums indexed [i][r]
#pragma unroll
    for (int i = 0; i < 4; ++i)
#pragma unroll
      for (int j = 0; j < 4; ++j)
#pragma unroll
        for (int r = 0; r < 4; ++r)
          sums[i][r] += __builtin_amdgcn_exp2f(acc[i][j][r]);
    __syncthreads();   // staged tile it+1 now visible
  }

  // reduce the 16 column-lanes holding the same row (XOR masks 1,2,4,8 keep lane>>4 fixed)
#pragma unroll
  for (int i = 0; i < 4; ++i)
#pragma unroll
    for (int r = 0; r < 4; ++r) {
      float v = sums[i][r];
      v += __shfl_xor(v, 1);
      v += __shfl_xor(v, 2);
      v += __shfl_xor(v, 4);
      v += __shfl_xor(v, 8);
      if ((lane & 15) == 0) {
        int grow = row0 + rows_off + i * 16 + (lane >> 4) * 4 + r;
        atomicAdd(&row_sums[grow], v);
      }
    }
}

// ---------- finish: loss_n = ln2*(64 + log2(sum_n) - s'_nn); mean over n ----------
__global__ void finish_kernel(const uint4* __restrict__ qa,
                              const uint4* __restrict__ tb,
                              const float* __restrict__ row_sums,
                              float* __restrict__ out) {
  int n = blockIdx.x * blockDim.x + threadIdx.x;   // 0..16383
  const uint4* a = qa + n * 8;   // 8 x 16B = 64 bf16 per row
  const uint4* b = tb + n * 8;
  float diag = 0.f;
#pragma unroll
  for (int c = 0; c < 8; ++c) {
    uint4 ua = a[c], ub = b[c];
    diag += blo(ua.x) * blo(ub.x) + bhi(ua.x) * bhi(ub.x);
    diag += blo(ua.y) * blo(ub.y) + bhi(ua.y) * bhi(ub.y);
    diag += blo(ua.z) * blo(ub.z) + bhi(ua.z) * bhi(ub.z);
    diag += blo(ua.w) * blo(ub.w) + bhi(ua.w) * bhi(ub.w);
  }
  float loss = LN2 * (SHIFT2 + log2f(row_sums[n]) - diag);
#pragma unroll
  for (int off = 32; off; off >>= 1) loss += __shfl_down(loss, off);
  if ((threadIdx.x & 63) == 0) atomicAdd(out, loss * (1.0f / N_ROWS));
}

extern "C" void kernel_launch(void* const* d_in, const int* in_sizes, int n_in,
                              void* d_out, int out_size, void* d_ws, size_t ws_size,
                              hipStream_t stream) {
  const float* logits  = (const float*)d_in[0];   // [16384][64] fp32
  const float* targets = (const float*)d_in[1];   // [16384][64] fp32
  const float* noise   = (const float*)d_in[2];   // [64] fp32
  float* out = (float*)d_out;

  uint8_t* ws = (uint8_t*)d_ws;
  uint8_t* qa = ws;                                  // bf16 q', 2 MB
  uint8_t* tb = ws + (size_t)2 * 1024 * 1024;        // bf16 targets, 2 MB
  float* row_sums = (float*)(ws + (size_t)4 * 1024 * 1024);  // 64 KB

  hipMemsetAsync(row_sums, 0, N_ROWS * sizeof(float), stream);
  hipMemsetAsync(out, 0, sizeof(float), stream);

  prep_kernel<<<1024, 256, 0, stream>>>(
      (const float4*)logits, (const float4*)targets, noise,
      (ushort4*)qa, (ushort4*)tb);

  flash_kernel<<<NSPLIT * (N_ROWS / BN), 256, 0, stream>>>(qa, tb, row_sums);

  finish_kernel<<<N_ROWS / 256, 256, 0, stream>>>(
      (const uint4*)qa, (const uint4*)tb, row_sums, out);
}

// Round 2
// 111.020 us; speedup vs baseline: 1.0658x; 1.0658x over previous
//
#include <hip/hip_runtime.h>
#include <hip/hip_bf16.h>
#include <stdint.h>

// Problem constants (fixed by reference: N=M=16384, D=64, T=1)
#define N_ROWS 16384
#define D_DIM 64
#define BN 128
#define BM 128
#define NSPLIT 8
#define COLS_PER_SPLIT (N_ROWS / NSPLIT)   // 2048
#define N_ITER (COLS_PER_SPLIT / BM)       // 16
#define SHIFT2 64.0f                        // LSE shift, log2 domain
#define LOG2E 1.44269504088896340736f
#define LN2 0.69314718055994530942f

using short8  = __attribute__((ext_vector_type(8))) short;
using float4v = __attribute__((ext_vector_type(4))) float;

// ---------- bf16 helpers (manual, version-independent) ----------
__device__ __forceinline__ unsigned short f2bf(float f) {
  unsigned u = __float_as_uint(f);
  unsigned r = (u + 0x7fffu + ((u >> 16) & 1u)) >> 16;   // RNE
  return (unsigned short)r;
}
__device__ __forceinline__ float blo(unsigned u) { return __uint_as_float(u << 16); }
__device__ __forceinline__ float bhi(unsigned u) { return __uint_as_float(u & 0xffff0000u); }

// ---------- async global->LDS 16B ----------
__device__ __forceinline__ void async_stage_16(const void* g, void* l) {
  __builtin_amdgcn_global_load_lds(
      (const __attribute__((address_space(1))) uint32_t*)g,
      (__attribute__((address_space(3))) uint32_t*)l, 16, 0, 0);
}

// Stage one 128-row x 64-bf16 (128 B/row) tile into LDS with XOR chunk swizzle.
// LDS slot (row, cs) holds global chunk c = cs ^ (row&7). 16 wave-instrs total,
// 4 per wave; instr t covers rows [t*8, t*8+8), lane supplies its own gaddr,
// dest is lds + t*1024 + lane*16 (contiguous in lane order per the HW rule).
__device__ __forceinline__ void stage_tile(const uint8_t* gbase, uint8_t* lds,
                                           int wave, int lane) {
#pragma unroll
  for (int q = 0; q < 4; ++q) {
    int t = wave * 4 + q;
    int row = t * 8 + (lane >> 3);
    int c = (lane & 7) ^ (row & 7);
    async_stage_16(gbase + row * 128 + c * 16, lds + t * 1024 + lane * 16);
  }
}

// ---------- prep: q' = logits*log2e - log2(noise) -> bf16 ; targets -> bf16 ----------
// Also zeroes row_sums and out (replaces two memset dispatches).
__global__ void prep_kernel(const float4* __restrict__ lg,
                            const float4* __restrict__ tg,
                            const float* __restrict__ noise,
                            ushort4* __restrict__ qa,
                            ushort4* __restrict__ tb,
                            float* __restrict__ row_sums,
                            float* __restrict__ out) {
  int i = blockIdx.x * blockDim.x + threadIdx.x;   // 0 .. 262143 (1M floats / 4)
  if (i < N_ROWS) row_sums[i] = 0.f;
  if (i == 0) out[0] = 0.f;
  int d4 = (i & 15) << 2;                          // 16 float4 per 64-elem row
  float4 l = lg[i];
  float4 t = tg[i];
  float c0 = log2f(noise[d4 + 0]);
  float c1 = log2f(noise[d4 + 1]);
  float c2 = log2f(noise[d4 + 2]);
  float c3 = log2f(noise[d4 + 3]);
  ushort4 ua, ub;
  ua.x = f2bf(l.x * LOG2E - c0);
  ua.y = f2bf(l.y * LOG2E - c1);
  ua.z = f2bf(l.z * LOG2E - c2);
  ua.w = f2bf(l.w * LOG2E - c3);
  ub.x = f2bf(t.x);
  ub.y = f2bf(t.y);
  ub.z = f2bf(t.z);
  ub.w = f2bf(t.w);
  qa[i] = ua;
  tb[i] = ub;
}

// ---------- flash: per-row sum of 2^(s' - 64) over this block's column split ----------
__global__ __launch_bounds__(256, 2) void flash_kernel(
    const uint8_t* __restrict__ qa,   // bf16 [16384][64], pre-scaled by log2e
    const uint8_t* __restrict__ tb,   // bf16 [16384][64]
    float* __restrict__ row_sums) {   // [16384], pre-zeroed
  __shared__ __align__(16) uint8_t ldsA[BN * 128];
  __shared__ __align__(16) uint8_t ldsB[BM * 128];

  const int bid = blockIdx.x;        // 0..1023
  const int rb = bid >> 3;           // row block 0..127
  const int sp = bid & 7;            // M split 0..7
  const int tid = threadIdx.x;
  const int wave = tid >> 6;
  const int lane = tid & 63;

  const int row0 = rb * BN;
  const int col0 = sp * COLS_PER_SPLIT;

  stage_tile(qa + (size_t)row0 * 128, ldsA, wave, lane);
  stage_tile(tb + (size_t)col0 * 128, ldsB, wave, lane);
  __syncthreads();

  const int rows_off = (wave >> 1) * 64;   // wave's 64-row region
  const int cols_off = (wave & 1) * 64;    // wave's 64-col region

  // A fragments are invariant across the whole M sweep: load once.
  short8 afrag[4][2];
#pragma unroll
  for (int i = 0; i < 4; ++i)
#pragma unroll
    for (int k2 = 0; k2 < 2; ++k2) {
      int r = rows_off + i * 16 + (lane & 15);
      int c = (k2 * 4 + (lane >> 4)) ^ (r & 7);
      afrag[i][k2] = *(const short8*)(ldsA + r * 128 + c * 16);
    }

  float sums[4][4];
#pragma unroll
  for (int i = 0; i < 4; ++i)
#pragma unroll
    for (int r = 0; r < 4; ++r) sums[i][r] = 0.f;

  for (int it = 0; it < N_ITER; ++it) {
    // read this tile's B fragments into registers
    short8 bfrag[4][2];
#pragma unroll
    for (int j = 0; j < 4; ++j)
#pragma unroll
      for (int k2 = 0; k2 < 2; ++k2) {
        int r = cols_off + j * 16 + (lane & 15);
        int c = (k2 * 4 + (lane >> 4)) ^ (r & 7);
        bfrag[j][k2] = *(const short8*)(ldsB + r * 128 + c * 16);
      }
    __syncthreads();   // all waves done reading ldsB
    if (it + 1 < N_ITER)
      stage_tile(tb + (size_t)(col0 + (it + 1) * BM) * 128, ldsB, wave, lane);

    // compute 64x64 scores for this wave; C init = -SHIFT2 folds the LSE shift
    float4v acc[4][4];
#pragma unroll
    for (int i = 0; i < 4; ++i)
#pragma unroll
      for (int j = 0; j < 4; ++j) {
        float4v a0 = {-SHIFT2, -SHIFT2, -SHIFT2, -SHIFT2};
        a0 = __builtin_amdgcn_mfma_f32_16x16x32_bf16(afrag[i][0], bfrag[j][0], a0, 0, 0, 0);
        a0 = __builtin_amdgcn_mfma_f32_16x16x32_bf16(afrag[i][1], bfrag[j][1], a0, 0, 0, 0);
        acc[i][j] = a0;
      }
    // exp2 + accumulate per-row partial sums
    // C layout: col = lane&15, row = (lane>>4)*4 + r  -> sums indexed [i][r]
#pragma unroll
    for (int i = 0; i < 4; ++i)
#pragma unroll
      for (int j = 0; j < 4; ++j)
#pragma unroll
        for (int r = 0; r < 4; ++r)
          sums[i][r] += __builtin_amdgcn_exp2f(acc[i][j][r]);
    __syncthreads();   // staged tile it+1 now visible
  }

  // reduce the 16 column-lanes holding the same row (XOR masks 1,2,4,8 keep lane>>4 fixed)
#pragma unroll
  for (int i = 0; i < 4; ++i)
#pragma unroll
    for (int r = 0; r < 4; ++r) {
      float v = sums[i][r];
      v += __shfl_xor(v, 1);
      v += __shfl_xor(v, 2);
      v += __shfl_xor(v, 4);
      v += __shfl_xor(v, 8);
      if ((lane & 15) == 0) {
        int grow = row0 + rows_off + i * 16 + (lane >> 4) * 4 + r;
        atomicAdd(&row_sums[grow], v);
      }
    }
}

// ---------- finish: loss_n = ln2*(64 + log2(sum_n) - s'_nn); mean over n ----------
__global__ void finish_kernel(const uint4* __restrict__ qa,
                              const uint4* __restrict__ tb,
                              const float* __restrict__ row_sums,
                              float* __restrict__ out) {
  int n = blockIdx.x * blockDim.x + threadIdx.x;   // 0..16383
  const uint4* a = qa + n * 8;   // 8 x 16B = 64 bf16 per row
  const uint4* b = tb + n * 8;
  float diag = 0.f;
#pragma unroll
  for (int c = 0; c < 8; ++c) {
    uint4 ua = a[c], ub = b[c];
    diag += blo(ua.x) * blo(ub.x) + bhi(ua.x) * bhi(ub.x);
    diag += blo(ua.y) * blo(ub.y) + bhi(ua.y) * bhi(ub.y);
    diag += blo(ua.z) * blo(ub.z) + bhi(ua.z) * bhi(ub.z);
    diag += blo(ua.w) * blo(ub.w) + bhi(ua.w) * bhi(ub.w);
  }
  float loss = LN2 * (SHIFT2 + log2f(row_sums[n]) - diag);
#pragma unroll
  for (int off = 32; off; off >>= 1) loss += __shfl_down(loss, off);
  if ((threadIdx.x & 63) == 0) atomicAdd(out, loss * (1.0f / N_ROWS));
}

extern "C" void kernel_launch(void* const* d_in, const int* in_sizes, int n_in,
                              void* d_out, int out_size, void* d_ws, size_t ws_size,
                              hipStream_t stream) {
  const float* logits  = (const float*)d_in[0];   // [16384][64] fp32
  const float* targets = (const float*)d_in[1];   // [16384][64] fp32
  const float* noise   = (const float*)d_in[2];   // [64] fp32
  float* out = (float*)d_out;

  uint8_t* ws = (uint8_t*)d_ws;
  uint8_t* qa = ws;                                  // bf16 q', 2 MB
  uint8_t* tb = ws + (size_t)2 * 1024 * 1024;        // bf16 targets, 2 MB
  float* row_sums = (float*)(ws + (size_t)4 * 1024 * 1024);  // 64 KB

  prep_kernel<<<1024, 256, 0, stream>>>(
      (const float4*)logits, (const float4*)targets, noise,
      (ushort4*)qa, (ushort4*)tb, row_sums, out);

  flash_kernel<<<NSPLIT * (N_ROWS / BN), 256, 0, stream>>>(qa, tb, row_sums);

  finish_kernel<<<N_ROWS / 256, 256, 0, stream>>>(
      (const uint4*)qa, (const uint4*)tb, row_sums, out);
}